// Round 1
// baseline (902.802 us; speedup 1.0000x reference)
//
#include <hip/hip_runtime.h>
#include <hip/hip_bf16.h>
#include <math.h>

// Problem constants (match reference)
#define NNODES 100000
#define NEDGES 1600000
#define DH 128
#define DOUT 40
#define EPSBN 1e-5f

// ---------------- degree / CSR build ----------------

__global__ void k_zero_counts(int* __restrict__ counts) {
    int i = blockIdx.x * blockDim.x + threadIdx.x;
    if (i < NNODES) counts[i] = 0;
}

__global__ void k_count(const int* __restrict__ ei, int* __restrict__ counts) {
    int e = blockIdx.x * blockDim.x + threadIdx.x;
    if (e < NEDGES) atomicAdd(&counts[ei[NEDGES + e]], 1);
}

__global__ void k_dinv(const int* __restrict__ counts, float* __restrict__ dinv) {
    int i = blockIdx.x * blockDim.x + threadIdx.x;
    if (i < NNODES) dinv[i] = 1.0f / sqrtf((float)counts[i] + 1.0f);
}

// per-block exclusive scan of counts -> row_start, block totals -> blockSums
__global__ void k_scan1(const int* __restrict__ counts, int* __restrict__ row_start,
                        int* __restrict__ blockSums) {
    __shared__ int s[256];
    int t = threadIdx.x;
    int g = blockIdx.x * 256 + t;
    int v = (g < NNODES) ? counts[g] : 0;
    s[t] = v;
    __syncthreads();
    for (int off = 1; off < 256; off <<= 1) {
        int x = (t >= off) ? s[t - off] : 0;
        __syncthreads();
        s[t] += x;
        __syncthreads();
    }
    if (g < NNODES) row_start[g] = s[t] - v;   // exclusive
    if (t == 255) blockSums[blockIdx.x] = s[255];
}

// single-block scan of block sums (nb <= 512) in-place -> exclusive
__global__ void k_scan2(int* __restrict__ blockSums, int nb) {
    __shared__ int s[512];
    int t = threadIdx.x;
    int v = (t < nb) ? blockSums[t] : 0;
    s[t] = v;
    __syncthreads();
    for (int off = 1; off < 512; off <<= 1) {
        int x = (t >= off) ? s[t - off] : 0;
        __syncthreads();
        s[t] += x;
        __syncthreads();
    }
    if (t < nb) blockSums[t] = s[t] - v;       // exclusive
}

__global__ void k_scan3(int* __restrict__ row_start, const int* __restrict__ blockSums,
                        int* __restrict__ cursor) {
    int g = blockIdx.x * 256 + threadIdx.x;
    if (g < NNODES) {
        int r = row_start[g] + blockSums[blockIdx.x];
        row_start[g] = r;
        cursor[g] = r;
    }
}

__global__ void k_fill(const int* __restrict__ ei, const float* __restrict__ dinv,
                       int* __restrict__ cursor, int* __restrict__ csr_src,
                       float* __restrict__ csr_norm) {
    int e = blockIdx.x * blockDim.x + threadIdx.x;
    if (e >= NEDGES) return;
    int src = ei[e];
    int dst = ei[NEDGES + e];
    float w = dinv[src] * dinv[dst];
    int p = atomicAdd(&cursor[dst], 1);
    csr_src[p] = src;
    csr_norm[p] = w;
}

// ---------------- GEMM: out[N][NC] = act(A)[N][128] @ W[128][NC] ----------------
// act = BN(scale,shift)+ReLU when BN=true, identity otherwise.

template <int NC, int NCT, int JT, bool BN>
__global__ __launch_bounds__(256) void k_gemm(const float* __restrict__ A,
                                              const float* __restrict__ W,
                                              float* __restrict__ out,
                                              const float* __restrict__ scale,
                                              const float* __restrict__ shift) {
    const int BM = 64, BK = 32;
    __shared__ float As[BK][68];   // [k][m], pad 68 keeps float4 alignment
    __shared__ float Bs[BK][NCT];
    int t = threadIdx.x;
    int tx = t & 15, ty = t >> 4;
    int r0 = blockIdx.x * BM;

    float acc[4][JT];
#pragma unroll
    for (int i = 0; i < 4; i++)
#pragma unroll
        for (int j = 0; j < JT; j++) acc[i][j] = 0.0f;

    for (int k0 = 0; k0 < 128; k0 += BK) {
        // A tile: 64 rows x 32 k, as float4 per thread x2
#pragma unroll
        for (int u = 0; u < 2; u++) {
            int idx = t + u * 256;           // 0..511
            int row = idx >> 3, c4 = idx & 7;
            int gr = r0 + row;
            float4 v = make_float4(0.f, 0.f, 0.f, 0.f);
            if (gr < NNODES)
                v = *reinterpret_cast<const float4*>(&A[(size_t)gr * 128 + k0 + c4 * 4]);
            if (BN) {
                int kc = k0 + c4 * 4;
                v.x = fmaxf(fmaf(v.x, scale[kc + 0], shift[kc + 0]), 0.f);
                v.y = fmaxf(fmaf(v.y, scale[kc + 1], shift[kc + 1]), 0.f);
                v.z = fmaxf(fmaf(v.z, scale[kc + 2], shift[kc + 2]), 0.f);
                v.w = fmaxf(fmaf(v.w, scale[kc + 3], shift[kc + 3]), 0.f);
            }
            As[c4 * 4 + 0][row] = v.x;
            As[c4 * 4 + 1][row] = v.y;
            As[c4 * 4 + 2][row] = v.z;
            As[c4 * 4 + 3][row] = v.w;
        }
        // B tile
        if (NC == 128) {
#pragma unroll
            for (int u = 0; u < 4; u++) {
                int idx = t + u * 256;        // 0..1023
                int k = idx >> 5, c4 = idx & 31;
                float4 v = *reinterpret_cast<const float4*>(&W[(size_t)(k0 + k) * NC + c4 * 4]);
                *reinterpret_cast<float4*>(&Bs[k][c4 * 4]) = v;
            }
        } else {
            for (int idx = t; idx < BK * NCT; idx += 256) {
                int k = idx / NCT, c = idx % NCT;
                Bs[k][c] = (c < NC) ? W[(size_t)(k0 + k) * NC + c] : 0.f;
            }
        }
        __syncthreads();
#pragma unroll
        for (int k = 0; k < BK; k++) {
            float a[4];
            *reinterpret_cast<float4*>(a) = *reinterpret_cast<const float4*>(&As[k][ty * 4]);
            float b[JT];
#pragma unroll
            for (int j = 0; j < JT; j++) b[j] = Bs[k][tx * JT + j];
#pragma unroll
            for (int i = 0; i < 4; i++)
#pragma unroll
                for (int j = 0; j < JT; j++) acc[i][j] = fmaf(a[i], b[j], acc[i][j]);
        }
        __syncthreads();
    }
    // store
#pragma unroll
    for (int i = 0; i < 4; i++) {
        int gr = r0 + ty * 4 + i;
        if (gr >= NNODES) continue;
        if (NC == 128) {
            float4 v0 = make_float4(acc[i][0], acc[i][1], acc[i][2], acc[i][3 % JT]);
            // JT==8 on this path; write two float4s
            *reinterpret_cast<float4*>(&out[(size_t)gr * 128 + tx * 8]) =
                make_float4(acc[i][0], acc[i][1], acc[i][2], acc[i][3]);
            *reinterpret_cast<float4*>(&out[(size_t)gr * 128 + tx * 8 + 4]) =
                make_float4(acc[i][4 % JT], acc[i][5 % JT], acc[i][6 % JT], acc[i][7 % JT]);
            (void)v0;
        } else {
#pragma unroll
            for (int j = 0; j < JT; j++) {
                int c = tx * JT + j;
                if (c < NC) out[(size_t)gr * NC + c] = acc[i][j];
            }
        }
    }
}

// ---------------- aggregation (pull via CSR), D=128 ----------------
// out[n] = h[n]*dinv[n]^2 + bias + sum_{e in CSR row n} h[src_e]*norm_e

__global__ __launch_bounds__(256) void k_agg128(const float* __restrict__ h,
                                                const float* __restrict__ dinv,
                                                const int* __restrict__ row_start,
                                                const int* __restrict__ counts,
                                                const int* __restrict__ csr_src,
                                                const float* __restrict__ csr_norm,
                                                const float* __restrict__ bias,
                                                float* __restrict__ out) {
    int wid = threadIdx.x >> 6, lane = threadIdx.x & 63;
    int n = blockIdx.x * 4 + wid;
    if (n >= NNODES) return;
    float di = dinv[n];
    float2 hv = *reinterpret_cast<const float2*>(&h[(size_t)n * 128 + lane * 2]);
    float2 acc;
    acc.x = hv.x * di * di + bias[lane * 2 + 0];
    acc.y = hv.y * di * di + bias[lane * 2 + 1];
    int s = row_start[n], len = counts[n];
    int i = 0;
    for (; i + 1 < len; i += 2) {
        int s0 = csr_src[s + i], s1 = csr_src[s + i + 1];
        float w0 = csr_norm[s + i], w1 = csr_norm[s + i + 1];
        float2 h0 = *reinterpret_cast<const float2*>(&h[(size_t)s0 * 128 + lane * 2]);
        float2 h1 = *reinterpret_cast<const float2*>(&h[(size_t)s1 * 128 + lane * 2]);
        acc.x += h0.x * w0 + h1.x * w1;
        acc.y += h0.y * w0 + h1.y * w1;
    }
    if (i < len) {
        int s0 = csr_src[s + i];
        float w0 = csr_norm[s + i];
        float2 h0 = *reinterpret_cast<const float2*>(&h[(size_t)s0 * 128 + lane * 2]);
        acc.x += h0.x * w0;
        acc.y += h0.y * w0;
    }
    *reinterpret_cast<float2*>(&out[(size_t)n * 128 + lane * 2]) = acc;
}

// ---------------- aggregation D=40 + fused log_softmax ----------------

__global__ __launch_bounds__(256) void k_agg40_lsm(const float* __restrict__ h,
                                                   const float* __restrict__ dinv,
                                                   const int* __restrict__ row_start,
                                                   const int* __restrict__ counts,
                                                   const int* __restrict__ csr_src,
                                                   const float* __restrict__ csr_norm,
                                                   const float* __restrict__ bias,
                                                   float* __restrict__ out) {
    int wid = threadIdx.x >> 6, lane = threadIdx.x & 63;
    int n = blockIdx.x * 4 + wid;
    if (n >= NNODES) return;
    float di = dinv[n];
    float acc = 0.f;
    if (lane < DOUT) acc = h[(size_t)n * DOUT + lane] * di * di + bias[lane];
    int s = row_start[n], len = counts[n];
    for (int i = 0; i < len; i++) {
        int s0 = csr_src[s + i];
        float w0 = csr_norm[s + i];
        if (lane < DOUT) acc += h[(size_t)s0 * DOUT + lane] * w0;
    }
    // log_softmax over lanes 0..39
    float m = (lane < DOUT) ? acc : -1e30f;
    for (int off = 32; off; off >>= 1) m = fmaxf(m, __shfl_xor(m, off));
    float e = (lane < DOUT) ? expf(acc - m) : 0.f;
    for (int off = 32; off; off >>= 1) e += __shfl_xor(e, off);
    if (lane < DOUT) out[(size_t)n * DOUT + lane] = acc - m - logf(e);
}

// ---------------- BatchNorm statistics ----------------

__global__ void k_zero_stats(double* __restrict__ colsum) {
    int t = threadIdx.x;
    if (t < 256) colsum[t] = 0.0;
}

__global__ __launch_bounds__(256) void k_stats(const float* __restrict__ buf,
                                               double* __restrict__ colsum) {
    int t = threadIdx.x;
    int col = t & 127;
    float sum = 0.f, sumsq = 0.f;
    long g0 = (long)blockIdx.x * 256 + t;
    long stride = (long)gridDim.x * 256;
    const long total = (long)NNODES * 128;
    for (long g = g0; g < total; g += stride) {
        float v = buf[g];
        sum += v;
        sumsq += v * v;
    }
    __shared__ float ls[256], lsq[256];
    ls[t] = sum;
    lsq[t] = sumsq;
    __syncthreads();
    if (t < 128) {
        double s = (double)ls[t] + (double)ls[t + 128];
        double sq = (double)lsq[t] + (double)lsq[t + 128];
        atomicAdd(&colsum[col], s);
        atomicAdd(&colsum[128 + col], sq);
    }
}

__global__ void k_bn_finalize(const double* __restrict__ colsum, const float* __restrict__ g,
                              const float* __restrict__ be, float* __restrict__ scale,
                              float* __restrict__ shift) {
    int c = threadIdx.x;
    if (c >= 128) return;
    double mu = colsum[c] / (double)NNODES;
    double var = colsum[128 + c] / (double)NNODES - mu * mu;
    float sc = g[c] * (1.0f / sqrtf((float)var + EPSBN));
    scale[c] = sc;
    shift[c] = be[c] - (float)mu * sc;
}

// ---------------- launch ----------------

extern "C" void kernel_launch(void* const* d_in, const int* in_sizes, int n_in,
                              void* d_out, int out_size, void* d_ws, size_t ws_size,
                              hipStream_t stream) {
    const float* x  = (const float*)d_in[0];
    const int* ei   = (const int*)d_in[1];
    const float* W1 = (const float*)d_in[2];
    const float* b1 = (const float*)d_in[3];
    const float* g1 = (const float*)d_in[4];
    const float* be1 = (const float*)d_in[5];
    const float* W2 = (const float*)d_in[6];
    const float* b2 = (const float*)d_in[7];
    const float* g2 = (const float*)d_in[8];
    const float* be2 = (const float*)d_in[9];
    const float* Wf = (const float*)d_in[10];
    const float* bf = (const float*)d_in[11];
    float* out = (float*)d_out;

    char* ws = (char*)d_ws;
    int*    counts    = (int*)(ws + 0);
    int*    row_start = (int*)(ws + 512ull * 1024);
    int*    cursor    = (int*)(ws + 1024ull * 1024);
    float*  dinv      = (float*)(ws + 1536ull * 1024);
    int*    blockSums = (int*)(ws + 2048ull * 1024);
    double* colsum    = (double*)(ws + 2304ull * 1024);
    float*  scale     = (float*)(ws + 2368ull * 1024);
    float*  shift     = (float*)(ws + 2372ull * 1024);
    int*    csr_src   = (int*)(ws + 3ull * 1024 * 1024);
    float*  csr_norm  = (float*)(ws + 10ull * 1024 * 1024);
    float*  bufA      = (float*)(ws + 17ull * 1024 * 1024);   // 51.2 MB
    float*  bufB      = (float*)(ws + 70ull * 1024 * 1024);   // 51.2 MB

    const int NB_N = (NNODES + 255) / 256;     // 391
    const int NB_E = (NEDGES + 255) / 256;     // 6250
    const int NB_G = (NNODES + 63) / 64;       // 1563 (gemm)
    const int NB_A = (NNODES + 3) / 4;         // 25000 (agg)

    // CSR build
    hipLaunchKernelGGL(k_zero_counts, dim3(NB_N), dim3(256), 0, stream, counts);
    hipLaunchKernelGGL(k_count, dim3(NB_E), dim3(256), 0, stream, ei, counts);
    hipLaunchKernelGGL(k_dinv, dim3(NB_N), dim3(256), 0, stream, counts, dinv);
    hipLaunchKernelGGL(k_scan1, dim3(NB_N), dim3(256), 0, stream, counts, row_start, blockSums);
    hipLaunchKernelGGL(k_scan2, dim3(1), dim3(512), 0, stream, blockSums, NB_N);
    hipLaunchKernelGGL(k_scan3, dim3(NB_N), dim3(256), 0, stream, row_start, blockSums, cursor);
    hipLaunchKernelGGL(k_fill, dim3(NB_E), dim3(256), 0, stream, ei, dinv, cursor, csr_src, csr_norm);

    // conv1: gemm + aggregate
    hipLaunchKernelGGL((k_gemm<128, 128, 8, false>), dim3(NB_G), dim3(256), 0, stream,
                       x, W1, bufA, (const float*)nullptr, (const float*)nullptr);
    hipLaunchKernelGGL(k_agg128, dim3(NB_A), dim3(256), 0, stream,
                       bufA, dinv, row_start, counts, csr_src, csr_norm, b1, bufB);
    // BN1 stats
    hipLaunchKernelGGL(k_zero_stats, dim3(1), dim3(256), 0, stream, colsum);
    hipLaunchKernelGGL(k_stats, dim3(1024), dim3(256), 0, stream, bufB, colsum);
    hipLaunchKernelGGL(k_bn_finalize, dim3(1), dim3(128), 0, stream, colsum, g1, be1, scale, shift);

    // conv2: gemm (fused BN1+ReLU on load) + aggregate
    hipLaunchKernelGGL((k_gemm<128, 128, 8, true>), dim3(NB_G), dim3(256), 0, stream,
                       bufB, W2, bufA, scale, shift);
    hipLaunchKernelGGL(k_agg128, dim3(NB_A), dim3(256), 0, stream,
                       bufA, dinv, row_start, counts, csr_src, csr_norm, b2, bufB);
    // BN2 stats
    hipLaunchKernelGGL(k_zero_stats, dim3(1), dim3(256), 0, stream, colsum);
    hipLaunchKernelGGL(k_stats, dim3(1024), dim3(256), 0, stream, bufB, colsum);
    hipLaunchKernelGGL(k_bn_finalize, dim3(1), dim3(128), 0, stream, colsum, g2, be2, scale, shift);

    // conv3: gemm (fused BN2+ReLU) + aggregate + fused log_softmax
    hipLaunchKernelGGL((k_gemm<40, 48, 3, true>), dim3(NB_G), dim3(256), 0, stream,
                       bufB, Wf, bufA, scale, shift);
    hipLaunchKernelGGL(k_agg40_lsm, dim3(NB_A), dim3(256), 0, stream,
                       bufA, dinv, row_start, counts, csr_src, csr_norm, bf, out);
}

// Round 2
// 829.853 us; speedup vs baseline: 1.0879x; 1.0879x over previous
//
#include <hip/hip_runtime.h>
#include <hip/hip_bf16.h>
#include <math.h>

// Problem constants (match reference)
#define NNODES 100000
#define NEDGES 1600000
#define DH 128
#define DOUT 40
#define EPSBN 1e-5f

// ---------------- degree / CSR build ----------------

__global__ void k_zero_counts(int* __restrict__ counts) {
    int i = blockIdx.x * blockDim.x + threadIdx.x;
    if (i < NNODES) counts[i] = 0;
}

__global__ void k_count(const int* __restrict__ ei, int* __restrict__ counts) {
    int e = blockIdx.x * blockDim.x + threadIdx.x;
    if (e < NEDGES) atomicAdd(&counts[ei[NEDGES + e]], 1);
}

__global__ void k_dinv(const int* __restrict__ counts, float* __restrict__ dinv) {
    int i = blockIdx.x * blockDim.x + threadIdx.x;
    if (i < NNODES) dinv[i] = 1.0f / sqrtf((float)counts[i] + 1.0f);
}

// per-block exclusive scan of counts -> row_start, block totals -> blockSums
__global__ void k_scan1(const int* __restrict__ counts, int* __restrict__ row_start,
                        int* __restrict__ blockSums) {
    __shared__ int s[256];
    int t = threadIdx.x;
    int g = blockIdx.x * 256 + t;
    int v = (g < NNODES) ? counts[g] : 0;
    s[t] = v;
    __syncthreads();
    for (int off = 1; off < 256; off <<= 1) {
        int x = (t >= off) ? s[t - off] : 0;
        __syncthreads();
        s[t] += x;
        __syncthreads();
    }
    if (g < NNODES) row_start[g] = s[t] - v;   // exclusive
    if (t == 255) blockSums[blockIdx.x] = s[255];
}

__global__ void k_scan2(int* __restrict__ blockSums, int nb) {
    __shared__ int s[512];
    int t = threadIdx.x;
    int v = (t < nb) ? blockSums[t] : 0;
    s[t] = v;
    __syncthreads();
    for (int off = 1; off < 512; off <<= 1) {
        int x = (t >= off) ? s[t - off] : 0;
        __syncthreads();
        s[t] += x;
        __syncthreads();
    }
    if (t < nb) blockSums[t] = s[t] - v;       // exclusive
}

__global__ void k_scan3(int* __restrict__ row_start, const int* __restrict__ blockSums,
                        int* __restrict__ cursor) {
    int g = blockIdx.x * 256 + threadIdx.x;
    if (g < NNODES) {
        int r = row_start[g] + blockSums[blockIdx.x];
        row_start[g] = r;
        cursor[g] = r;
    }
}

// csr entry: {src_index, norm_weight_bits} packed so the agg loop does ONE 8B load/edge
__global__ void k_fill(const int* __restrict__ ei, const float* __restrict__ dinv,
                       int* __restrict__ cursor, int2* __restrict__ csr) {
    int e = blockIdx.x * blockDim.x + threadIdx.x;
    if (e >= NEDGES) return;
    int src = ei[e];
    int dst = ei[NEDGES + e];
    float w = dinv[src] * dinv[dst];
    int p = atomicAdd(&cursor[dst], 1);
    csr[p] = make_int2(src, __float_as_int(w));
}

// ---------------- GEMM: out[N][128] = act(A)[N][128] @ W[128][128] ----------------

template <bool BN>
__global__ __launch_bounds__(256) void k_gemm128(const float* __restrict__ A,
                                                 const float* __restrict__ W,
                                                 float* __restrict__ out,
                                                 const float* __restrict__ scale,
                                                 const float* __restrict__ shift) {
    const int BM = 64, BK = 32;
    __shared__ float As[BK][68];
    __shared__ float Bs[BK][128];
    int t = threadIdx.x;
    int tx = t & 15, ty = t >> 4;
    int r0 = blockIdx.x * BM;

    float acc[4][8];
#pragma unroll
    for (int i = 0; i < 4; i++)
#pragma unroll
        for (int j = 0; j < 8; j++) acc[i][j] = 0.0f;

    for (int k0 = 0; k0 < 128; k0 += BK) {
#pragma unroll
        for (int u = 0; u < 2; u++) {
            int idx = t + u * 256;
            int row = idx >> 3, c4 = idx & 7;
            int gr = r0 + row;
            float4 v = make_float4(0.f, 0.f, 0.f, 0.f);
            if (gr < NNODES)
                v = *reinterpret_cast<const float4*>(&A[(size_t)gr * 128 + k0 + c4 * 4]);
            if (BN) {
                int kc = k0 + c4 * 4;
                v.x = fmaxf(fmaf(v.x, scale[kc + 0], shift[kc + 0]), 0.f);
                v.y = fmaxf(fmaf(v.y, scale[kc + 1], shift[kc + 1]), 0.f);
                v.z = fmaxf(fmaf(v.z, scale[kc + 2], shift[kc + 2]), 0.f);
                v.w = fmaxf(fmaf(v.w, scale[kc + 3], shift[kc + 3]), 0.f);
            }
            As[c4 * 4 + 0][row] = v.x;
            As[c4 * 4 + 1][row] = v.y;
            As[c4 * 4 + 2][row] = v.z;
            As[c4 * 4 + 3][row] = v.w;
        }
#pragma unroll
        for (int u = 0; u < 4; u++) {
            int idx = t + u * 256;
            int k = idx >> 5, c4 = idx & 31;
            *reinterpret_cast<float4*>(&Bs[k][c4 * 4]) =
                *reinterpret_cast<const float4*>(&W[(size_t)(k0 + k) * 128 + c4 * 4]);
        }
        __syncthreads();
#pragma unroll
        for (int k = 0; k < BK; k++) {
            float a[4];
            *reinterpret_cast<float4*>(a) = *reinterpret_cast<const float4*>(&As[k][ty * 4]);
            float b[8];
#pragma unroll
            for (int j = 0; j < 8; j++) b[j] = Bs[k][tx * 8 + j];
#pragma unroll
            for (int i = 0; i < 4; i++)
#pragma unroll
                for (int j = 0; j < 8; j++) acc[i][j] = fmaf(a[i], b[j], acc[i][j]);
        }
        __syncthreads();
    }
#pragma unroll
    for (int i = 0; i < 4; i++) {
        int gr = r0 + ty * 4 + i;
        if (gr >= NNODES) continue;
        *reinterpret_cast<float4*>(&out[(size_t)gr * 128 + tx * 8]) =
            make_float4(acc[i][0], acc[i][1], acc[i][2], acc[i][3]);
        *reinterpret_cast<float4*>(&out[(size_t)gr * 128 + tx * 8 + 4]) =
            make_float4(acc[i][4], acc[i][5], acc[i][6], acc[i][7]);
    }
}

// ---------------- GEMM 128->40 with bias + log_softmax epilogue ----------------

__global__ __launch_bounds__(256) void k_gemm40_lsm(const float* __restrict__ A,
                                                    const float* __restrict__ W,
                                                    const float* __restrict__ bias,
                                                    float* __restrict__ out) {
    const int BM = 64, BK = 32;
    __shared__ float As[BK][68];
    __shared__ float Bs[BK][48];
    int t = threadIdx.x;
    int tx = t & 15, ty = t >> 4;
    int r0 = blockIdx.x * BM;

    float acc[4][3];
#pragma unroll
    for (int i = 0; i < 4; i++)
#pragma unroll
        for (int j = 0; j < 3; j++) acc[i][j] = 0.0f;

    for (int k0 = 0; k0 < 128; k0 += BK) {
#pragma unroll
        for (int u = 0; u < 2; u++) {
            int idx = t + u * 256;
            int row = idx >> 3, c4 = idx & 7;
            int gr = r0 + row;
            float4 v = make_float4(0.f, 0.f, 0.f, 0.f);
            if (gr < NNODES)
                v = *reinterpret_cast<const float4*>(&A[(size_t)gr * 128 + k0 + c4 * 4]);
            As[c4 * 4 + 0][row] = v.x;
            As[c4 * 4 + 1][row] = v.y;
            As[c4 * 4 + 2][row] = v.z;
            As[c4 * 4 + 3][row] = v.w;
        }
        for (int idx = t; idx < BK * 48; idx += 256) {
            int k = idx / 48, c = idx % 48;
            Bs[k][c] = (c < DOUT) ? W[(size_t)(k0 + k) * DOUT + c] : 0.f;
        }
        __syncthreads();
#pragma unroll
        for (int k = 0; k < BK; k++) {
            float a[4];
            *reinterpret_cast<float4*>(a) = *reinterpret_cast<const float4*>(&As[k][ty * 4]);
            float b[3];
#pragma unroll
            for (int j = 0; j < 3; j++) b[j] = Bs[k][tx * 3 + j];
#pragma unroll
            for (int i = 0; i < 4; i++)
#pragma unroll
                for (int j = 0; j < 3; j++) acc[i][j] = fmaf(a[i], b[j], acc[i][j]);
        }
        __syncthreads();
    }
    // epilogue: +bias, then per-row log_softmax (row split across 16 lanes of same ty)
#pragma unroll
    for (int i = 0; i < 4; i++) {
        int gr = r0 + ty * 4 + i;
        float v[3];
        float m = -1e30f;
#pragma unroll
        for (int j = 0; j < 3; j++) {
            int c = tx * 3 + j;
            v[j] = (c < DOUT) ? acc[i][j] + bias[c] : -1e30f;
            m = fmaxf(m, v[j]);
        }
#pragma unroll
        for (int off = 8; off; off >>= 1) m = fmaxf(m, __shfl_xor(m, off));
        float es = 0.f;
#pragma unroll
        for (int j = 0; j < 3; j++)
            if (tx * 3 + j < DOUT) es += expf(v[j] - m);
#pragma unroll
        for (int off = 8; off; off >>= 1) es += __shfl_xor(es, off);
        float lse = m + logf(es);
        if (gr < NNODES) {
#pragma unroll
            for (int j = 0; j < 3; j++) {
                int c = tx * 3 + j;
                if (c < DOUT) out[(size_t)gr * DOUT + c] = v[j] - lse;
            }
        }
    }
}

// ---------------- aggregation (pull via CSR), D=128, 8-deep gather pipeline ----
// out[n] = act(h[n])*dinv[n]^2 + (bias) + sum_{e in row n} act(h[src_e])*norm_e
// act = identity or BN(scale,shift)+ReLU

template <bool BN, bool BIAS>
__global__ __launch_bounds__(256) void k_agg128(const float* __restrict__ h,
                                                const float* __restrict__ dinv,
                                                const int* __restrict__ row_start,
                                                const int* __restrict__ counts,
                                                const int2* __restrict__ csr,
                                                const float* __restrict__ bias,
                                                const float* __restrict__ scale,
                                                const float* __restrict__ shift,
                                                float* __restrict__ out) {
    int wid = threadIdx.x >> 6, lane = threadIdx.x & 63;
    int n = blockIdx.x * 4 + wid;
    if (n >= NNODES) return;
    float2 sc = make_float2(1.f, 1.f), sh = make_float2(0.f, 0.f);
    if (BN) {
        sc = *reinterpret_cast<const float2*>(&scale[lane * 2]);
        sh = *reinterpret_cast<const float2*>(&shift[lane * 2]);
    }
    float di = dinv[n];
    float2 hv = *reinterpret_cast<const float2*>(&h[(size_t)n * 128 + lane * 2]);
    if (BN) {
        hv.x = fmaxf(fmaf(hv.x, sc.x, sh.x), 0.f);
        hv.y = fmaxf(fmaf(hv.y, sc.y, sh.y), 0.f);
    }
    float2 acc;
    acc.x = hv.x * di * di;
    acc.y = hv.y * di * di;
    if (BIAS) {
        float2 bv = *reinterpret_cast<const float2*>(&bias[lane * 2]);
        acc.x += bv.x;
        acc.y += bv.y;
    }
    int s = row_start[n], len = counts[n];

    int i = 0;
    for (; i + 8 <= len; i += 8) {
        int2 e[8];
#pragma unroll
        for (int u = 0; u < 8; u++) e[u] = csr[s + i + u];
        float2 g[8];
#pragma unroll
        for (int u = 0; u < 8; u++)
            g[u] = *reinterpret_cast<const float2*>(&h[(size_t)e[u].x * 128 + lane * 2]);
#pragma unroll
        for (int u = 0; u < 8; u++) {
            float w = __int_as_float(e[u].y);
            float2 v = g[u];
            if (BN) {
                v.x = fmaxf(fmaf(v.x, sc.x, sh.x), 0.f);
                v.y = fmaxf(fmaf(v.y, sc.y, sh.y), 0.f);
            }
            acc.x = fmaf(v.x, w, acc.x);
            acc.y = fmaf(v.y, w, acc.y);
        }
    }
    int r = len - i;   // 0..7 tail, mask-padded: idx 0, weight 0 (h[0] is valid memory)
    if (r > 0) {
        int2 e[8];
#pragma unroll
        for (int u = 0; u < 8; u++)
            e[u] = (u < r) ? csr[s + i + u] : make_int2(0, 0);
        float2 g[8];
#pragma unroll
        for (int u = 0; u < 8; u++)
            g[u] = *reinterpret_cast<const float2*>(&h[(size_t)e[u].x * 128 + lane * 2]);
#pragma unroll
        for (int u = 0; u < 8; u++) {
            float w = __int_as_float(e[u].y);
            float2 v = g[u];
            if (BN) {
                v.x = fmaxf(fmaf(v.x, sc.x, sh.x), 0.f);
                v.y = fmaxf(fmaf(v.y, sc.y, sh.y), 0.f);
            }
            acc.x = fmaf(v.x, w, acc.x);
            acc.y = fmaf(v.y, w, acc.y);
        }
    }
    *reinterpret_cast<float2*>(&out[(size_t)n * 128 + lane * 2]) = acc;
}

// ---------------- BatchNorm statistics ----------------

__global__ void k_zero_stats(double* __restrict__ colsum) {
    int t = threadIdx.x;
    if (t < 256) colsum[t] = 0.0;
}

__global__ __launch_bounds__(256) void k_stats(const float* __restrict__ buf,
                                               double* __restrict__ colsum) {
    int t = threadIdx.x;
    int col = t & 127;
    float sum = 0.f, sumsq = 0.f;
    long g0 = (long)blockIdx.x * 256 + t;
    long stride = (long)gridDim.x * 256;
    const long total = (long)NNODES * 128;
    for (long g = g0; g < total; g += stride) {
        float v = buf[g];
        sum += v;
        sumsq += v * v;
    }
    __shared__ float ls[256], lsq[256];
    ls[t] = sum;
    lsq[t] = sumsq;
    __syncthreads();
    if (t < 128) {
        double s = (double)ls[t] + (double)ls[t + 128];
        double sq = (double)lsq[t] + (double)lsq[t + 128];
        atomicAdd(&colsum[col], s);
        atomicAdd(&colsum[128 + col], sq);
    }
}

__global__ void k_bn_finalize(const double* __restrict__ colsum, const float* __restrict__ g,
                              const float* __restrict__ be, float* __restrict__ scale,
                              float* __restrict__ shift) {
    int c = threadIdx.x;
    if (c >= 128) return;
    double mu = colsum[c] / (double)NNODES;
    double var = colsum[128 + c] / (double)NNODES - mu * mu;
    float sc = g[c] * (1.0f / sqrtf((float)var + EPSBN));
    scale[c] = sc;
    shift[c] = be[c] - (float)mu * sc;
}

// ---------------- launch ----------------

extern "C" void kernel_launch(void* const* d_in, const int* in_sizes, int n_in,
                              void* d_out, int out_size, void* d_ws, size_t ws_size,
                              hipStream_t stream) {
    const float* x  = (const float*)d_in[0];
    const int* ei   = (const int*)d_in[1];
    const float* W1 = (const float*)d_in[2];
    const float* b1 = (const float*)d_in[3];
    const float* g1 = (const float*)d_in[4];
    const float* be1 = (const float*)d_in[5];
    const float* W2 = (const float*)d_in[6];
    const float* b2 = (const float*)d_in[7];
    const float* g2 = (const float*)d_in[8];
    const float* be2 = (const float*)d_in[9];
    const float* Wf = (const float*)d_in[10];
    const float* bf = (const float*)d_in[11];
    float* out = (float*)d_out;

    char* ws = (char*)d_ws;
    int*    counts    = (int*)(ws + 0);
    int*    row_start = (int*)(ws + 512ull * 1024);
    int*    cursor    = (int*)(ws + 1024ull * 1024);
    float*  dinv      = (float*)(ws + 1536ull * 1024);
    int*    blockSums = (int*)(ws + 2048ull * 1024);
    double* colsum    = (double*)(ws + 2304ull * 1024);
    float*  scale     = (float*)(ws + 2368ull * 1024);
    float*  shift     = (float*)(ws + 2372ull * 1024);
    int2*   csr       = (int2*)(ws + 3ull * 1024 * 1024);   // 12.8 MB + tail slack
    float*  bufA      = (float*)(ws + 17ull * 1024 * 1024); // 51.2 MB
    float*  bufB      = (float*)(ws + 70ull * 1024 * 1024); // 51.2 MB

    const int NB_N = (NNODES + 255) / 256;     // 391
    const int NB_E = (NEDGES + 255) / 256;     // 6250
    const int NB_G = (NNODES + 63) / 64;       // 1563 (gemm)
    const int NB_A = (NNODES + 3) / 4;         // 25000 (agg)

    // CSR build
    hipLaunchKernelGGL(k_zero_counts, dim3(NB_N), dim3(256), 0, stream, counts);
    hipLaunchKernelGGL(k_count, dim3(NB_E), dim3(256), 0, stream, ei, counts);
    hipLaunchKernelGGL(k_dinv, dim3(NB_N), dim3(256), 0, stream, counts, dinv);
    hipLaunchKernelGGL(k_scan1, dim3(NB_N), dim3(256), 0, stream, counts, row_start, blockSums);
    hipLaunchKernelGGL(k_scan2, dim3(1), dim3(512), 0, stream, blockSums, NB_N);
    hipLaunchKernelGGL(k_scan3, dim3(NB_N), dim3(256), 0, stream, row_start, blockSums, cursor);
    hipLaunchKernelGGL(k_fill, dim3(NB_E), dim3(256), 0, stream, ei, dinv, cursor, csr);

    // conv1: gemm + aggregate(+b1)
    hipLaunchKernelGGL((k_gemm128<false>), dim3(NB_G), dim3(256), 0, stream,
                       x, W1, bufA, (const float*)nullptr, (const float*)nullptr);
    hipLaunchKernelGGL((k_agg128<false, true>), dim3(NB_A), dim3(256), 0, stream,
                       bufA, dinv, row_start, counts, csr, b1,
                       (const float*)nullptr, (const float*)nullptr, bufB);
    // BN1 stats
    hipLaunchKernelGGL(k_zero_stats, dim3(1), dim3(256), 0, stream, colsum);
    hipLaunchKernelGGL(k_stats, dim3(1024), dim3(256), 0, stream, bufB, colsum);
    hipLaunchKernelGGL(k_bn_finalize, dim3(1), dim3(128), 0, stream, colsum, g1, be1, scale, shift);

    // conv2: gemm (fused BN1+ReLU on load) + aggregate(+b2)
    hipLaunchKernelGGL((k_gemm128<true>), dim3(NB_G), dim3(256), 0, stream,
                       bufB, W2, bufA, scale, shift);
    hipLaunchKernelGGL((k_agg128<false, true>), dim3(NB_A), dim3(256), 0, stream,
                       bufA, dinv, row_start, counts, csr, b2,
                       (const float*)nullptr, (const float*)nullptr, bufB);
    // BN2 stats
    hipLaunchKernelGGL(k_zero_stats, dim3(1), dim3(256), 0, stream, colsum);
    hipLaunchKernelGGL(k_stats, dim3(1024), dim3(256), 0, stream, bufB, colsum);
    hipLaunchKernelGGL(k_bn_finalize, dim3(1), dim3(128), 0, stream, colsum, g2, be2, scale, shift);

    // conv3 restructured: agg(act) first (BN2+ReLU fused on gather), then GEMM->40 + lsm.
    // agg(act @ Wf) == agg(act) @ Wf since aggregation is linear.
    hipLaunchKernelGGL((k_agg128<true, false>), dim3(NB_A), dim3(256), 0, stream,
                       bufB, dinv, row_start, counts, csr, (const float*)nullptr,
                       scale, shift, bufA);
    hipLaunchKernelGGL(k_gemm40_lsm, dim3(NB_G), dim3(256), 0, stream, bufA, Wf, bf, out);
}

// Round 4
// 806.613 us; speedup vs baseline: 1.1193x; 1.0288x over previous
//
#include <hip/hip_runtime.h>
#include <hip/hip_bf16.h>
#include <math.h>

// Problem constants (match reference)
#define NNODES 100000
#define NEDGES 1600000
#define DH 128
#define DOUT 40
#define EPSBN 1e-5f

// ---------------- degree / CSR build ----------------

__global__ void k_zero_counts(int* __restrict__ counts) {
    int i = blockIdx.x * blockDim.x + threadIdx.x;
    if (i < NNODES) counts[i] = 0;
}

__global__ void k_count(const int* __restrict__ ei, int* __restrict__ counts) {
    int e = blockIdx.x * blockDim.x + threadIdx.x;
    if (e < NEDGES) atomicAdd(&counts[ei[NEDGES + e]], 1);
}

__global__ void k_dinv(const int* __restrict__ counts, float* __restrict__ dinv) {
    int i = blockIdx.x * blockDim.x + threadIdx.x;
    if (i < NNODES) dinv[i] = 1.0f / sqrtf((float)counts[i] + 1.0f);
}

// per-block exclusive scan of counts -> row_start, block totals -> blockSums
__global__ void k_scan1(const int* __restrict__ counts, int* __restrict__ row_start,
                        int* __restrict__ blockSums) {
    __shared__ int s[256];
    int t = threadIdx.x;
    int g = blockIdx.x * 256 + t;
    int v = (g < NNODES) ? counts[g] : 0;
    s[t] = v;
    __syncthreads();
    for (int off = 1; off < 256; off <<= 1) {
        int x = (t >= off) ? s[t - off] : 0;
        __syncthreads();
        s[t] += x;
        __syncthreads();
    }
    if (g < NNODES) row_start[g] = s[t] - v;   // exclusive
    if (t == 255) blockSums[blockIdx.x] = s[255];
}

__global__ void k_scan2(int* __restrict__ blockSums, int nb) {
    __shared__ int s[512];
    int t = threadIdx.x;
    int v = (t < nb) ? blockSums[t] : 0;
    s[t] = v;
    __syncthreads();
    for (int off = 1; off < 512; off <<= 1) {
        int x = (t >= off) ? s[t - off] : 0;
        __syncthreads();
        s[t] += x;
        __syncthreads();
    }
    if (t < nb) blockSums[t] = s[t] - v;       // exclusive
}

__global__ void k_scan3(int* __restrict__ row_start, const int* __restrict__ blockSums,
                        int* __restrict__ cursor) {
    int g = blockIdx.x * 256 + threadIdx.x;
    if (g < NNODES) {
        int r = row_start[g] + blockSums[blockIdx.x];
        row_start[g] = r;
        cursor[g] = r;
    }
}

// csr entry: {src_index, norm_weight_bits} packed so the agg loop does ONE 8B load/edge
__global__ void k_fill(const int* __restrict__ ei, const float* __restrict__ dinv,
                       int* __restrict__ cursor, int2* __restrict__ csr) {
    int e = blockIdx.x * blockDim.x + threadIdx.x;
    if (e >= NEDGES) return;
    int src = ei[e];
    int dst = ei[NEDGES + e];
    float w = dinv[src] * dinv[dst];
    int p = atomicAdd(&cursor[dst], 1);
    csr[p] = make_int2(src, __float_as_int(w));
}

// ---------------- GEMM: out[N][128] = act(A)[N][128] @ W[128][128] ----------------

template <bool BN>
__global__ __launch_bounds__(256) void k_gemm128(const float* __restrict__ A,
                                                 const float* __restrict__ W,
                                                 float* __restrict__ out,
                                                 const float* __restrict__ scale,
                                                 const float* __restrict__ shift) {
    const int BM = 64, BK = 32;
    __shared__ float As[BK][68];
    __shared__ float Bs[BK][128];
    int t = threadIdx.x;
    int tx = t & 15, ty = t >> 4;
    int r0 = blockIdx.x * BM;

    float acc[4][8];
#pragma unroll
    for (int i = 0; i < 4; i++)
#pragma unroll
        for (int j = 0; j < 8; j++) acc[i][j] = 0.0f;

    for (int k0 = 0; k0 < 128; k0 += BK) {
#pragma unroll
        for (int u = 0; u < 2; u++) {
            int idx = t + u * 256;
            int row = idx >> 3, c4 = idx & 7;
            int gr = r0 + row;
            float4 v = make_float4(0.f, 0.f, 0.f, 0.f);
            if (gr < NNODES)
                v = *reinterpret_cast<const float4*>(&A[(size_t)gr * 128 + k0 + c4 * 4]);
            if (BN) {
                int kc = k0 + c4 * 4;
                v.x = fmaxf(fmaf(v.x, scale[kc + 0], shift[kc + 0]), 0.f);
                v.y = fmaxf(fmaf(v.y, scale[kc + 1], shift[kc + 1]), 0.f);
                v.z = fmaxf(fmaf(v.z, scale[kc + 2], shift[kc + 2]), 0.f);
                v.w = fmaxf(fmaf(v.w, scale[kc + 3], shift[kc + 3]), 0.f);
            }
            As[c4 * 4 + 0][row] = v.x;
            As[c4 * 4 + 1][row] = v.y;
            As[c4 * 4 + 2][row] = v.z;
            As[c4 * 4 + 3][row] = v.w;
        }
#pragma unroll
        for (int u = 0; u < 4; u++) {
            int idx = t + u * 256;
            int k = idx >> 5, c4 = idx & 31;
            *reinterpret_cast<float4*>(&Bs[k][c4 * 4]) =
                *reinterpret_cast<const float4*>(&W[(size_t)(k0 + k) * 128 + c4 * 4]);
        }
        __syncthreads();
#pragma unroll
        for (int k = 0; k < BK; k++) {
            float a[4];
            *reinterpret_cast<float4*>(a) = *reinterpret_cast<const float4*>(&As[k][ty * 4]);
            float b[8];
#pragma unroll
            for (int j = 0; j < 8; j++) b[j] = Bs[k][tx * 8 + j];
#pragma unroll
            for (int i = 0; i < 4; i++)
#pragma unroll
                for (int j = 0; j < 8; j++) acc[i][j] = fmaf(a[i], b[j], acc[i][j]);
        }
        __syncthreads();
    }
#pragma unroll
    for (int i = 0; i < 4; i++) {
        int gr = r0 + ty * 4 + i;
        if (gr >= NNODES) continue;
        *reinterpret_cast<float4*>(&out[(size_t)gr * 128 + tx * 8]) =
            make_float4(acc[i][0], acc[i][1], acc[i][2], acc[i][3]);
        *reinterpret_cast<float4*>(&out[(size_t)gr * 128 + tx * 8 + 4]) =
            make_float4(acc[i][4], acc[i][5], acc[i][6], acc[i][7]);
    }
}

// ---------------- GEMM 128->40 with bias + log_softmax epilogue ----------------

__global__ __launch_bounds__(256) void k_gemm40_lsm(const float* __restrict__ A,
                                                    const float* __restrict__ W,
                                                    const float* __restrict__ bias,
                                                    float* __restrict__ out) {
    const int BM = 64, BK = 32;
    __shared__ float As[BK][68];
    __shared__ float Bs[BK][48];
    int t = threadIdx.x;
    int tx = t & 15, ty = t >> 4;
    int r0 = blockIdx.x * BM;

    float acc[4][3];
#pragma unroll
    for (int i = 0; i < 4; i++)
#pragma unroll
        for (int j = 0; j < 3; j++) acc[i][j] = 0.0f;

    for (int k0 = 0; k0 < 128; k0 += BK) {
#pragma unroll
        for (int u = 0; u < 2; u++) {
            int idx = t + u * 256;
            int row = idx >> 3, c4 = idx & 7;
            int gr = r0 + row;
            float4 v = make_float4(0.f, 0.f, 0.f, 0.f);
            if (gr < NNODES)
                v = *reinterpret_cast<const float4*>(&A[(size_t)gr * 128 + k0 + c4 * 4]);
            As[c4 * 4 + 0][row] = v.x;
            As[c4 * 4 + 1][row] = v.y;
            As[c4 * 4 + 2][row] = v.z;
            As[c4 * 4 + 3][row] = v.w;
        }
        for (int idx = t; idx < BK * 48; idx += 256) {
            int k = idx / 48, c = idx % 48;
            Bs[k][c] = (c < DOUT) ? W[(size_t)(k0 + k) * DOUT + c] : 0.f;
        }
        __syncthreads();
#pragma unroll
        for (int k = 0; k < BK; k++) {
            float a[4];
            *reinterpret_cast<float4*>(a) = *reinterpret_cast<const float4*>(&As[k][ty * 4]);
            float b[3];
#pragma unroll
            for (int j = 0; j < 3; j++) b[j] = Bs[k][tx * 3 + j];
#pragma unroll
            for (int i = 0; i < 4; i++)
#pragma unroll
                for (int j = 0; j < 3; j++) acc[i][j] = fmaf(a[i], b[j], acc[i][j]);
        }
        __syncthreads();
    }
    // epilogue: +bias, then per-row log_softmax (row split across 16 lanes of same ty)
#pragma unroll
    for (int i = 0; i < 4; i++) {
        int gr = r0 + ty * 4 + i;
        float v[3];
        float m = -1e30f;
#pragma unroll
        for (int j = 0; j < 3; j++) {
            int c = tx * 3 + j;
            v[j] = (c < DOUT) ? acc[i][j] + bias[c] : -1e30f;
            m = fmaxf(m, v[j]);
        }
#pragma unroll
        for (int off = 8; off; off >>= 1) m = fmaxf(m, __shfl_xor(m, off));
        float es = 0.f;
#pragma unroll
        for (int j = 0; j < 3; j++)
            if (tx * 3 + j < DOUT) es += expf(v[j] - m);
#pragma unroll
        for (int off = 8; off; off >>= 1) es += __shfl_xor(es, off);
        float lse = m + logf(es);
        if (gr < NNODES) {
#pragma unroll
            for (int j = 0; j < 3; j++) {
                int c = tx * 3 + j;
                if (c < DOUT) out[(size_t)gr * DOUT + c] = v[j] - lse;
            }
        }
    }
}

// ---------------- aggregation (pull via CSR), D=128 ----------------
// 2 edges per wave in flight: lanes 0-31 take even edges, lanes 32-63 odd edges.
// Each lane loads float4 (16B) -> 32 lanes cover the 512B row. Halves combined
// at the end via __shfl_xor(,32). 4 pairs (8 edges) unrolled per iteration.
// out[n] = act(h[n])*dinv[n]^2 + (bias) + sum_{e in row n} act(h[src_e])*norm_e

template <bool BN, bool BIAS>
__global__ __launch_bounds__(256) void k_agg128(const float* __restrict__ h,
                                                const float* __restrict__ dinv,
                                                const int* __restrict__ row_start,
                                                const int* __restrict__ counts,
                                                const int2* __restrict__ csr,
                                                const float* __restrict__ bias,
                                                const float* __restrict__ scale,
                                                const float* __restrict__ shift,
                                                float* __restrict__ out) {
    int wid = threadIdx.x >> 6, lane = threadIdx.x & 63;
    int n = blockIdx.x * 4 + wid;
    if (n >= NNODES) return;
    int half = lane >> 5;          // 0: even edges + self, 1: odd edges
    int c0 = (lane & 31) * 4;      // column base for this lane's float4

    float4 sc4 = make_float4(1.f, 1.f, 1.f, 1.f);
    float4 sh4 = make_float4(0.f, 0.f, 0.f, 0.f);
    if (BN) {
        sc4 = *reinterpret_cast<const float4*>(&scale[c0]);
        sh4 = *reinterpret_cast<const float4*>(&shift[c0]);
    }

    float4 acc = make_float4(0.f, 0.f, 0.f, 0.f);
    float di = dinv[n];
    if (half == 0) {
        float4 hv = *reinterpret_cast<const float4*>(&h[(size_t)n * 128 + c0]);
        if (BN) {
            hv.x = fmaxf(fmaf(hv.x, sc4.x, sh4.x), 0.f);
            hv.y = fmaxf(fmaf(hv.y, sc4.y, sh4.y), 0.f);
            hv.z = fmaxf(fmaf(hv.z, sc4.z, sh4.z), 0.f);
            hv.w = fmaxf(fmaf(hv.w, sc4.w, sh4.w), 0.f);
        }
        float d2 = di * di;
        acc.x = hv.x * d2;
        acc.y = hv.y * d2;
        acc.z = hv.z * d2;
        acc.w = hv.w * d2;
        if (BIAS) {
            float4 bv = *reinterpret_cast<const float4*>(&bias[c0]);
            acc.x += bv.x;
            acc.y += bv.y;
            acc.z += bv.z;
            acc.w += bv.w;
        }
    }

    int s = row_start[n], len = counts[n];
    int i = 0;
    for (; i + 8 <= len; i += 8) {
        int2 e[4];
#pragma unroll
        for (int u = 0; u < 4; u++) e[u] = csr[s + i + u * 2 + half];
        float4 g[4];
#pragma unroll
        for (int u = 0; u < 4; u++)
            g[u] = *reinterpret_cast<const float4*>(&h[(size_t)e[u].x * 128 + c0]);
#pragma unroll
        for (int u = 0; u < 4; u++) {
            float w = __int_as_float(e[u].y);
            float4 v = g[u];
            if (BN) {
                v.x = fmaxf(fmaf(v.x, sc4.x, sh4.x), 0.f);
                v.y = fmaxf(fmaf(v.y, sc4.y, sh4.y), 0.f);
                v.z = fmaxf(fmaf(v.z, sc4.z, sh4.z), 0.f);
                v.w = fmaxf(fmaf(v.w, sc4.w, sh4.w), 0.f);
            }
            acc.x = fmaf(v.x, w, acc.x);
            acc.y = fmaf(v.y, w, acc.y);
            acc.z = fmaf(v.z, w, acc.z);
            acc.w = fmaf(v.w, w, acc.w);
        }
    }
    int r = len - i;   // 0..7 remaining; mask-padded (idx 0 / weight 0; h[0] is valid)
    if (r > 0) {
        int2 e[4];
#pragma unroll
        for (int u = 0; u < 4; u++) {
            int idx = i + u * 2 + half;
            e[u] = (idx < len) ? csr[s + idx] : make_int2(0, 0);
        }
        float4 g[4];
#pragma unroll
        for (int u = 0; u < 4; u++)
            g[u] = *reinterpret_cast<const float4*>(&h[(size_t)e[u].x * 128 + c0]);
#pragma unroll
        for (int u = 0; u < 4; u++) {
            float w = __int_as_float(e[u].y);
            float4 v = g[u];
            if (BN) {
                v.x = fmaxf(fmaf(v.x, sc4.x, sh4.x), 0.f);
                v.y = fmaxf(fmaf(v.y, sc4.y, sh4.y), 0.f);
                v.z = fmaxf(fmaf(v.z, sc4.z, sh4.z), 0.f);
                v.w = fmaxf(fmaf(v.w, sc4.w, sh4.w), 0.f);
            }
            acc.x = fmaf(v.x, w, acc.x);
            acc.y = fmaf(v.y, w, acc.y);
            acc.z = fmaf(v.z, w, acc.z);
            acc.w = fmaf(v.w, w, acc.w);
        }
    }

    // combine even/odd halves; lanes 0-31 hold the full row after the adds
    acc.x += __shfl_xor(acc.x, 32);
    acc.y += __shfl_xor(acc.y, 32);
    acc.z += __shfl_xor(acc.z, 32);
    acc.w += __shfl_xor(acc.w, 32);
    if (half == 0)
        *reinterpret_cast<float4*>(&out[(size_t)n * 128 + c0]) = acc;
}

// ---------------- BatchNorm statistics (float4 loads) ----------------

__global__ void k_zero_stats(double* __restrict__ colsum) {
    int t = threadIdx.x;
    if (t < 256) colsum[t] = 0.0;
}

__global__ __launch_bounds__(256) void k_stats(const float* __restrict__ buf,
                                               double* __restrict__ colsum) {
    int t = threadIdx.x;
    int cb = (t & 31) * 4;          // this thread's 4-column base (stride 256 == 0 mod 32)
    float4 s = make_float4(0.f, 0.f, 0.f, 0.f);
    float4 q = make_float4(0.f, 0.f, 0.f, 0.f);
    const float4* b4 = reinterpret_cast<const float4*>(buf);
    const long total4 = (long)NNODES * 32;
    for (long g = (long)blockIdx.x * 256 + t; g < total4; g += (long)gridDim.x * 256) {
        float4 v = b4[g];
        s.x += v.x; q.x += v.x * v.x;
        s.y += v.y; q.y += v.y * v.y;
        s.z += v.z; q.z += v.z * v.z;
        s.w += v.w; q.w += v.w * v.w;
    }
    __shared__ float ls[128][9];    // [col][group], pad 9 avoids bank conflicts
    __shared__ float lq[128][9];
    int grp = t >> 5;               // 8 groups of 32 threads share each col-base
    ls[cb + 0][grp] = s.x; lq[cb + 0][grp] = q.x;
    ls[cb + 1][grp] = s.y; lq[cb + 1][grp] = q.y;
    ls[cb + 2][grp] = s.z; lq[cb + 2][grp] = q.z;
    ls[cb + 3][grp] = s.w; lq[cb + 3][grp] = q.w;
    __syncthreads();
    if (t < 128) {
        double ds = 0.0, dq = 0.0;
#pragma unroll
        for (int j = 0; j < 8; j++) { ds += ls[t][j]; dq += lq[t][j]; }
        atomicAdd(&colsum[t], ds);
        atomicAdd(&colsum[128 + t], dq);
    }
}

__global__ void k_bn_finalize(const double* __restrict__ colsum, const float* __restrict__ g,
                              const float* __restrict__ be, float* __restrict__ scale,
                              float* __restrict__ shift) {
    int c = threadIdx.x;
    if (c >= 128) return;
    double mu = colsum[c] / (double)NNODES;
    double var = colsum[128 + c] / (double)NNODES - mu * mu;
    float sc = g[c] * (1.0f / sqrtf((float)var + EPSBN));
    scale[c] = sc;
    shift[c] = be[c] - (float)mu * sc;
}

// ---------------- launch ----------------

extern "C" void kernel_launch(void* const* d_in, const int* in_sizes, int n_in,
                              void* d_out, int out_size, void* d_ws, size_t ws_size,
                              hipStream_t stream) {
    const float* x  = (const float*)d_in[0];
    const int* ei   = (const int*)d_in[1];
    const float* W1 = (const float*)d_in[2];
    const float* b1 = (const float*)d_in[3];
    const float* g1 = (const float*)d_in[4];
    const float* be1 = (const float*)d_in[5];
    const float* W2 = (const float*)d_in[6];
    const float* b2 = (const float*)d_in[7];
    const float* g2 = (const float*)d_in[8];
    const float* be2 = (const float*)d_in[9];
    const float* Wf = (const float*)d_in[10];
    const float* bf = (const float*)d_in[11];
    float* out = (float*)d_out;

    char* ws = (char*)d_ws;
    int*    counts    = (int*)(ws + 0);
    int*    row_start = (int*)(ws + 512ull * 1024);
    int*    cursor    = (int*)(ws + 1024ull * 1024);
    float*  dinv      = (float*)(ws + 1536ull * 1024);
    int*    blockSums = (int*)(ws + 2048ull * 1024);
    double* colsum    = (double*)(ws + 2304ull * 1024);
    float*  scale     = (float*)(ws + 2368ull * 1024);
    float*  shift     = (float*)(ws + 2372ull * 1024);
    int2*   csr       = (int2*)(ws + 3ull * 1024 * 1024);   // 12.8 MB + tail slack
    float*  bufA      = (float*)(ws + 17ull * 1024 * 1024); // 51.2 MB
    float*  bufB      = (float*)(ws + 70ull * 1024 * 1024); // 51.2 MB

    const int NB_N = (NNODES + 255) / 256;     // 391
    const int NB_E = (NEDGES + 255) / 256;     // 6250
    const int NB_G = (NNODES + 63) / 64;       // 1563 (gemm)
    const int NB_A = (NNODES + 3) / 4;         // 25000 (agg)

    // CSR build
    hipLaunchKernelGGL(k_zero_counts, dim3(NB_N), dim3(256), 0, stream, counts);
    hipLaunchKernelGGL(k_count, dim3(NB_E), dim3(256), 0, stream, ei, counts);
    hipLaunchKernelGGL(k_dinv, dim3(NB_N), dim3(256), 0, stream, counts, dinv);
    hipLaunchKernelGGL(k_scan1, dim3(NB_N), dim3(256), 0, stream, counts, row_start, blockSums);
    hipLaunchKernelGGL(k_scan2, dim3(1), dim3(512), 0, stream, blockSums, NB_N);
    hipLaunchKernelGGL(k_scan3, dim3(NB_N), dim3(256), 0, stream, row_start, blockSums, cursor);
    hipLaunchKernelGGL(k_fill, dim3(NB_E), dim3(256), 0, stream, ei, dinv, cursor, csr);

    // conv1: gemm + aggregate(+b1)
    hipLaunchKernelGGL((k_gemm128<false>), dim3(NB_G), dim3(256), 0, stream,
                       x, W1, bufA, (const float*)nullptr, (const float*)nullptr);
    hipLaunchKernelGGL((k_agg128<false, true>), dim3(NB_A), dim3(256), 0, stream,
                       bufA, dinv, row_start, counts, csr, b1,
                       (const float*)nullptr, (const float*)nullptr, bufB);
    // BN1 stats
    hipLaunchKernelGGL(k_zero_stats, dim3(1), dim3(256), 0, stream, colsum);
    hipLaunchKernelGGL(k_stats, dim3(1024), dim3(256), 0, stream, bufB, colsum);
    hipLaunchKernelGGL(k_bn_finalize, dim3(1), dim3(128), 0, stream, colsum, g1, be1, scale, shift);

    // conv2: gemm (fused BN1+ReLU on load) + aggregate(+b2)
    hipLaunchKernelGGL((k_gemm128<true>), dim3(NB_G), dim3(256), 0, stream,
                       bufB, W2, bufA, scale, shift);
    hipLaunchKernelGGL((k_agg128<false, true>), dim3(NB_A), dim3(256), 0, stream,
                       bufA, dinv, row_start, counts, csr, b2,
                       (const float*)nullptr, (const float*)nullptr, bufB);
    // BN2 stats
    hipLaunchKernelGGL(k_zero_stats, dim3(1), dim3(256), 0, stream, colsum);
    hipLaunchKernelGGL(k_stats, dim3(1024), dim3(256), 0, stream, bufB, colsum);
    hipLaunchKernelGGL(k_bn_finalize, dim3(1), dim3(128), 0, stream, colsum, g2, be2, scale, shift);

    // conv3 restructured: agg(act) first (BN2+ReLU fused on gather), then GEMM->40 + lsm.
    // agg(act @ Wf) == agg(act) @ Wf since aggregation is linear.
    hipLaunchKernelGGL((k_agg128<true, false>), dim3(NB_A), dim3(256), 0, stream,
                       bufB, dinv, row_start, counts, csr, (const float*)nullptr,
                       scale, shift, bufA);
    hipLaunchKernelGGL(k_gemm40_lsm, dim3(NB_G), dim3(256), 0, stream, bufA, Wf, bf, out);
}

// Round 5
// 665.067 us; speedup vs baseline: 1.3575x; 1.2128x over previous
//
#include <hip/hip_runtime.h>
#include <hip/hip_bf16.h>
#include <hip/hip_fp16.h>
#include <math.h>

// Problem constants (match reference)
#define NNODES 100000
#define NEDGES 1600000
#define DH 128
#define DOUT 40
#define EPSBN 1e-5f

// ---------------- degree / CSR build ----------------

__global__ void k_zero_counts(int* __restrict__ counts) {
    int i = blockIdx.x * blockDim.x + threadIdx.x;
    if (i < NNODES) counts[i] = 0;
}

__global__ void k_count(const int* __restrict__ ei, int* __restrict__ counts) {
    int e = blockIdx.x * blockDim.x + threadIdx.x;
    if (e < NEDGES) atomicAdd(&counts[ei[NEDGES + e]], 1);
}

__global__ void k_dinv(const int* __restrict__ counts, float* __restrict__ dinv) {
    int i = blockIdx.x * blockDim.x + threadIdx.x;
    if (i < NNODES) dinv[i] = 1.0f / sqrtf((float)counts[i] + 1.0f);
}

// per-block exclusive scan of counts -> row_start, block totals -> blockSums
__global__ void k_scan1(const int* __restrict__ counts, int* __restrict__ row_start,
                        int* __restrict__ blockSums) {
    __shared__ int s[256];
    int t = threadIdx.x;
    int g = blockIdx.x * 256 + t;
    int v = (g < NNODES) ? counts[g] : 0;
    s[t] = v;
    __syncthreads();
    for (int off = 1; off < 256; off <<= 1) {
        int x = (t >= off) ? s[t - off] : 0;
        __syncthreads();
        s[t] += x;
        __syncthreads();
    }
    if (g < NNODES) row_start[g] = s[t] - v;   // exclusive
    if (t == 255) blockSums[blockIdx.x] = s[255];
}

__global__ void k_scan2(int* __restrict__ blockSums, int nb) {
    __shared__ int s[512];
    int t = threadIdx.x;
    int v = (t < nb) ? blockSums[t] : 0;
    s[t] = v;
    __syncthreads();
    for (int off = 1; off < 512; off <<= 1) {
        int x = (t >= off) ? s[t - off] : 0;
        __syncthreads();
        s[t] += x;
        __syncthreads();
    }
    if (t < nb) blockSums[t] = s[t] - v;       // exclusive
}

__global__ void k_scan3(int* __restrict__ row_start, const int* __restrict__ blockSums,
                        int* __restrict__ cursor) {
    int g = blockIdx.x * 256 + threadIdx.x;
    if (g < NNODES) {
        int r = row_start[g] + blockSums[blockIdx.x];
        row_start[g] = r;
        cursor[g] = r;
    }
}

// csr entry: {src_index, norm_weight_bits} packed so the agg loop does ONE 8B load/edge
__global__ void k_fill(const int* __restrict__ ei, const float* __restrict__ dinv,
                       int* __restrict__ cursor, int2* __restrict__ csr) {
    int e = blockIdx.x * blockDim.x + threadIdx.x;
    if (e >= NEDGES) return;
    int src = ei[e];
    int dst = ei[NEDGES + e];
    float w = dinv[src] * dinv[dst];
    int p = atomicAdd(&cursor[dst], 1);
    csr[p] = make_int2(src, __float_as_int(w));
}

// ---------------- GEMM: out16[N][128] = act(A)[N][128] @ W[128][128], fp16 out ----

template <bool BN>
__global__ __launch_bounds__(256) void k_gemm128(const float* __restrict__ A,
                                                 const float* __restrict__ W,
                                                 __half* __restrict__ out,
                                                 const float* __restrict__ scale,
                                                 const float* __restrict__ shift) {
    const int BM = 64, BK = 32;
    __shared__ float As[BK][68];
    __shared__ float Bs[BK][128];
    int t = threadIdx.x;
    int tx = t & 15, ty = t >> 4;
    int r0 = blockIdx.x * BM;

    float acc[4][8];
#pragma unroll
    for (int i = 0; i < 4; i++)
#pragma unroll
        for (int j = 0; j < 8; j++) acc[i][j] = 0.0f;

    for (int k0 = 0; k0 < 128; k0 += BK) {
#pragma unroll
        for (int u = 0; u < 2; u++) {
            int idx = t + u * 256;
            int row = idx >> 3, c4 = idx & 7;
            int gr = r0 + row;
            float4 v = make_float4(0.f, 0.f, 0.f, 0.f);
            if (gr < NNODES)
                v = *reinterpret_cast<const float4*>(&A[(size_t)gr * 128 + k0 + c4 * 4]);
            if (BN) {
                int kc = k0 + c4 * 4;
                v.x = fmaxf(fmaf(v.x, scale[kc + 0], shift[kc + 0]), 0.f);
                v.y = fmaxf(fmaf(v.y, scale[kc + 1], shift[kc + 1]), 0.f);
                v.z = fmaxf(fmaf(v.z, scale[kc + 2], shift[kc + 2]), 0.f);
                v.w = fmaxf(fmaf(v.w, scale[kc + 3], shift[kc + 3]), 0.f);
            }
            As[c4 * 4 + 0][row] = v.x;
            As[c4 * 4 + 1][row] = v.y;
            As[c4 * 4 + 2][row] = v.z;
            As[c4 * 4 + 3][row] = v.w;
        }
#pragma unroll
        for (int u = 0; u < 4; u++) {
            int idx = t + u * 256;
            int k = idx >> 5, c4 = idx & 31;
            *reinterpret_cast<float4*>(&Bs[k][c4 * 4]) =
                *reinterpret_cast<const float4*>(&W[(size_t)(k0 + k) * 128 + c4 * 4]);
        }
        __syncthreads();
#pragma unroll
        for (int k = 0; k < BK; k++) {
            float a[4];
            *reinterpret_cast<float4*>(a) = *reinterpret_cast<const float4*>(&As[k][ty * 4]);
            float b[8];
#pragma unroll
            for (int j = 0; j < 8; j++) b[j] = Bs[k][tx * 8 + j];
#pragma unroll
            for (int i = 0; i < 4; i++)
#pragma unroll
                for (int j = 0; j < 8; j++) acc[i][j] = fmaf(a[i], b[j], acc[i][j]);
        }
        __syncthreads();
    }
#pragma unroll
    for (int i = 0; i < 4; i++) {
        int gr = r0 + ty * 4 + i;
        if (gr >= NNODES) continue;
        __half hv[8] __attribute__((aligned(16)));
#pragma unroll
        for (int j = 0; j < 8; j++) hv[j] = __float2half_rn(acc[i][j]);
        *reinterpret_cast<uint4*>(&out[(size_t)gr * 128 + tx * 8]) =
            *reinterpret_cast<const uint4*>(hv);
    }
}

// ---------------- GEMM 128->40 (fp32 in) with bias + log_softmax epilogue -------

__global__ __launch_bounds__(256) void k_gemm40_lsm(const float* __restrict__ A,
                                                    const float* __restrict__ W,
                                                    const float* __restrict__ bias,
                                                    float* __restrict__ out) {
    const int BM = 64, BK = 32;
    __shared__ float As[BK][68];
    __shared__ float Bs[BK][48];
    int t = threadIdx.x;
    int tx = t & 15, ty = t >> 4;
    int r0 = blockIdx.x * BM;

    float acc[4][3];
#pragma unroll
    for (int i = 0; i < 4; i++)
#pragma unroll
        for (int j = 0; j < 3; j++) acc[i][j] = 0.0f;

    for (int k0 = 0; k0 < 128; k0 += BK) {
#pragma unroll
        for (int u = 0; u < 2; u++) {
            int idx = t + u * 256;
            int row = idx >> 3, c4 = idx & 7;
            int gr = r0 + row;
            float4 v = make_float4(0.f, 0.f, 0.f, 0.f);
            if (gr < NNODES)
                v = *reinterpret_cast<const float4*>(&A[(size_t)gr * 128 + k0 + c4 * 4]);
            As[c4 * 4 + 0][row] = v.x;
            As[c4 * 4 + 1][row] = v.y;
            As[c4 * 4 + 2][row] = v.z;
            As[c4 * 4 + 3][row] = v.w;
        }
        for (int idx = t; idx < BK * 48; idx += 256) {
            int k = idx / 48, c = idx % 48;
            Bs[k][c] = (c < DOUT) ? W[(size_t)(k0 + k) * DOUT + c] : 0.f;
        }
        __syncthreads();
#pragma unroll
        for (int k = 0; k < BK; k++) {
            float a[4];
            *reinterpret_cast<float4*>(a) = *reinterpret_cast<const float4*>(&As[k][ty * 4]);
            float b[3];
#pragma unroll
            for (int j = 0; j < 3; j++) b[j] = Bs[k][tx * 3 + j];
#pragma unroll
            for (int i = 0; i < 4; i++)
#pragma unroll
                for (int j = 0; j < 3; j++) acc[i][j] = fmaf(a[i], b[j], acc[i][j]);
        }
        __syncthreads();
    }
    // epilogue: +bias, then per-row log_softmax (row split across 16 lanes of same ty)
#pragma unroll
    for (int i = 0; i < 4; i++) {
        int gr = r0 + ty * 4 + i;
        float v[3];
        float m = -1e30f;
#pragma unroll
        for (int j = 0; j < 3; j++) {
            int c = tx * 3 + j;
            v[j] = (c < DOUT) ? acc[i][j] + bias[c] : -1e30f;
            m = fmaxf(m, v[j]);
        }
#pragma unroll
        for (int off = 8; off; off >>= 1) m = fmaxf(m, __shfl_xor(m, off));
        float es = 0.f;
#pragma unroll
        for (int j = 0; j < 3; j++)
            if (tx * 3 + j < DOUT) es += expf(v[j] - m);
#pragma unroll
        for (int off = 8; off; off >>= 1) es += __shfl_xor(es, off);
        float lse = m + logf(es);
        if (gr < NNODES) {
#pragma unroll
            for (int j = 0; j < 3; j++) {
                int c = tx * 3 + j;
                if (c < DOUT) out[(size_t)gr * DOUT + c] = v[j] - lse;
            }
        }
    }
}

// ---------------- aggregation (pull via CSR), fp16 rows ----------------
// One wave per dst row. 4 edge slots (16 lanes each); each lane loads uint4 =
// 8 halves (16B) -> 16 lanes cover the 256B fp16 row. 8 edges in flight per
// iteration (2 per slot). Quarter-wave results combined via shfl_xor(16|32).
// out32[n] = act(h[n])*dinv^2 + (bias) + sum act(h[src])*w ; optional raw fp16 copy.

template <bool BN>
__device__ __forceinline__ void accum8(float (&acc)[8], uint4 raw, float w,
                                       const float (&sc)[8], const float (&sh)[8]) {
    const __half2* hp = reinterpret_cast<const __half2*>(&raw);
#pragma unroll
    for (int p = 0; p < 4; p++) {
        float2 f = __half22float2(hp[p]);
        if (BN) {
            f.x = fmaxf(fmaf(f.x, sc[2 * p + 0], sh[2 * p + 0]), 0.f);
            f.y = fmaxf(fmaf(f.y, sc[2 * p + 1], sh[2 * p + 1]), 0.f);
        }
        acc[2 * p + 0] = fmaf(f.x, w, acc[2 * p + 0]);
        acc[2 * p + 1] = fmaf(f.y, w, acc[2 * p + 1]);
    }
}

template <bool BN, bool BIAS, bool W16>
__global__ __launch_bounds__(256) void k_aggh(const __half* __restrict__ h,
                                              const float* __restrict__ dinv,
                                              const int* __restrict__ row_start,
                                              const int* __restrict__ counts,
                                              const int2* __restrict__ csr,
                                              const float* __restrict__ bias,
                                              const float* __restrict__ scale,
                                              const float* __restrict__ shift,
                                              float* __restrict__ out,
                                              __half* __restrict__ out16) {
    int wid = threadIdx.x >> 6, lane = threadIdx.x & 63;
    int n = blockIdx.x * 4 + wid;
    if (n >= NNODES) return;
    int slot = lane >> 4;          // 0..3 edge slot
    int c0 = (lane & 15) * 8;      // this lane's 8-column base

    float sc[8], sh[8];
    if (BN) {
        *reinterpret_cast<float4*>(&sc[0]) = *reinterpret_cast<const float4*>(&scale[c0]);
        *reinterpret_cast<float4*>(&sc[4]) = *reinterpret_cast<const float4*>(&scale[c0 + 4]);
        *reinterpret_cast<float4*>(&sh[0]) = *reinterpret_cast<const float4*>(&shift[c0]);
        *reinterpret_cast<float4*>(&sh[4]) = *reinterpret_cast<const float4*>(&shift[c0 + 4]);
    }

    float acc[8];
#pragma unroll
    for (int j = 0; j < 8; j++) acc[j] = 0.f;

    // self-loop term on slot 0
    if (slot == 0) {
        float di = dinv[n];
        float d2 = di * di;
        uint4 raw = *reinterpret_cast<const uint4*>(&h[(size_t)n * 128 + c0]);
        const __half2* hp = reinterpret_cast<const __half2*>(&raw);
#pragma unroll
        for (int p = 0; p < 4; p++) {
            float2 f = __half22float2(hp[p]);
            if (BN) {
                f.x = fmaxf(fmaf(f.x, sc[2 * p + 0], sh[2 * p + 0]), 0.f);
                f.y = fmaxf(fmaf(f.y, sc[2 * p + 1], sh[2 * p + 1]), 0.f);
            }
            acc[2 * p + 0] = f.x * d2;
            acc[2 * p + 1] = f.y * d2;
        }
        if (BIAS) {
            float bv[8];
            *reinterpret_cast<float4*>(&bv[0]) = *reinterpret_cast<const float4*>(&bias[c0]);
            *reinterpret_cast<float4*>(&bv[4]) = *reinterpret_cast<const float4*>(&bias[c0 + 4]);
#pragma unroll
            for (int j = 0; j < 8; j++) acc[j] += bv[j];
        }
    }

    int s = row_start[n], len = counts[n];
    int i = 0;
    for (; i + 8 <= len; i += 8) {
        int2 e0 = csr[s + i + slot];
        int2 e1 = csr[s + i + 4 + slot];
        uint4 r0 = *reinterpret_cast<const uint4*>(&h[(size_t)e0.x * 128 + c0]);
        uint4 r1 = *reinterpret_cast<const uint4*>(&h[(size_t)e1.x * 128 + c0]);
        accum8<BN>(acc, r0, __int_as_float(e0.y), sc, sh);
        accum8<BN>(acc, r1, __int_as_float(e1.y), sc, sh);
    }
    if (i < len) {   // masked tail: idx 0 / weight 0 (h[0] is valid memory)
        int i0 = i + slot, i1 = i + 4 + slot;
        int2 e0 = (i0 < len) ? csr[s + i0] : make_int2(0, 0);
        int2 e1 = (i1 < len) ? csr[s + i1] : make_int2(0, 0);
        uint4 r0 = *reinterpret_cast<const uint4*>(&h[(size_t)e0.x * 128 + c0]);
        uint4 r1 = *reinterpret_cast<const uint4*>(&h[(size_t)e1.x * 128 + c0]);
        accum8<BN>(acc, r0, __int_as_float(e0.y), sc, sh);
        accum8<BN>(acc, r1, __int_as_float(e1.y), sc, sh);
    }

    // combine 4 slots; all lanes end with the full sum
#pragma unroll
    for (int j = 0; j < 8; j++) {
        acc[j] += __shfl_xor(acc[j], 16);
        acc[j] += __shfl_xor(acc[j], 32);
    }
    if (slot == 0) {
        *reinterpret_cast<float4*>(&out[(size_t)n * 128 + c0]) =
            make_float4(acc[0], acc[1], acc[2], acc[3]);
        *reinterpret_cast<float4*>(&out[(size_t)n * 128 + c0 + 4]) =
            make_float4(acc[4], acc[5], acc[6], acc[7]);
        if (W16) {
            __half hv[8] __attribute__((aligned(16)));
#pragma unroll
            for (int j = 0; j < 8; j++) hv[j] = __float2half_rn(acc[j]);
            *reinterpret_cast<uint4*>(&out16[(size_t)n * 128 + c0]) =
                *reinterpret_cast<const uint4*>(hv);
        }
    }
}

// ---------------- BatchNorm statistics (float4 loads) ----------------

__global__ void k_zero_stats(double* __restrict__ colsum) {
    int t = threadIdx.x;
    if (t < 256) colsum[t] = 0.0;
}

__global__ __launch_bounds__(256) void k_stats(const float* __restrict__ buf,
                                               double* __restrict__ colsum) {
    int t = threadIdx.x;
    int cb = (t & 31) * 4;          // this thread's 4-column base (stride 256 == 0 mod 32)
    float4 s = make_float4(0.f, 0.f, 0.f, 0.f);
    float4 q = make_float4(0.f, 0.f, 0.f, 0.f);
    const float4* b4 = reinterpret_cast<const float4*>(buf);
    const long total4 = (long)NNODES * 32;
    for (long g = (long)blockIdx.x * 256 + t; g < total4; g += (long)gridDim.x * 256) {
        float4 v = b4[g];
        s.x += v.x; q.x += v.x * v.x;
        s.y += v.y; q.y += v.y * v.y;
        s.z += v.z; q.z += v.z * v.z;
        s.w += v.w; q.w += v.w * v.w;
    }
    __shared__ float ls[128][9];    // [col][group], pad 9 avoids bank conflicts
    __shared__ float lq[128][9];
    int grp = t >> 5;               // 8 groups of 32 threads share each col-base
    ls[cb + 0][grp] = s.x; lq[cb + 0][grp] = q.x;
    ls[cb + 1][grp] = s.y; lq[cb + 1][grp] = q.y;
    ls[cb + 2][grp] = s.z; lq[cb + 2][grp] = q.z;
    ls[cb + 3][grp] = s.w; lq[cb + 3][grp] = q.w;
    __syncthreads();
    if (t < 128) {
        double ds = 0.0, dq = 0.0;
#pragma unroll
        for (int j = 0; j < 8; j++) { ds += ls[t][j]; dq += lq[t][j]; }
        atomicAdd(&colsum[t], ds);
        atomicAdd(&colsum[128 + t], dq);
    }
}

__global__ void k_bn_finalize(const double* __restrict__ colsum, const float* __restrict__ g,
                              const float* __restrict__ be, float* __restrict__ scale,
                              float* __restrict__ shift) {
    int c = threadIdx.x;
    if (c >= 128) return;
    double mu = colsum[c] / (double)NNODES;
    double var = colsum[128 + c] / (double)NNODES - mu * mu;
    float sc = g[c] * (1.0f / sqrtf((float)var + EPSBN));
    scale[c] = sc;
    shift[c] = be[c] - (float)mu * sc;
}

// ---------------- launch ----------------

extern "C" void kernel_launch(void* const* d_in, const int* in_sizes, int n_in,
                              void* d_out, int out_size, void* d_ws, size_t ws_size,
                              hipStream_t stream) {
    const float* x  = (const float*)d_in[0];
    const int* ei   = (const int*)d_in[1];
    const float* W1 = (const float*)d_in[2];
    const float* b1 = (const float*)d_in[3];
    const float* g1 = (const float*)d_in[4];
    const float* be1 = (const float*)d_in[5];
    const float* W2 = (const float*)d_in[6];
    const float* b2 = (const float*)d_in[7];
    const float* g2 = (const float*)d_in[8];
    const float* be2 = (const float*)d_in[9];
    const float* Wf = (const float*)d_in[10];
    const float* bf = (const float*)d_in[11];
    float* out = (float*)d_out;

    char* ws = (char*)d_ws;
    int*    counts    = (int*)(ws + 0);
    int*    row_start = (int*)(ws + 512ull * 1024);
    int*    cursor    = (int*)(ws + 1024ull * 1024);
    float*  dinv      = (float*)(ws + 1536ull * 1024);
    int*    blockSums = (int*)(ws + 2048ull * 1024);
    double* colsum    = (double*)(ws + 2304ull * 1024);
    float*  scale     = (float*)(ws + 2368ull * 1024);
    float*  shift     = (float*)(ws + 2372ull * 1024);
    int2*   csr       = (int2*)(ws + 3ull * 1024 * 1024);     // 12.8 MB
    __half* h16       = (__half*)(ws + 16ull * 1024 * 1024);  // 25.6 MB (h1, then h2)
    __half* z16       = (__half*)(ws + 42ull * 1024 * 1024);  // 25.6 MB (raw z2 copy)
    float*  zbuf      = (float*)(ws + 68ull * 1024 * 1024);   // 51.2 MB (z1 -> z2 -> a3)

    const int NB_N = (NNODES + 255) / 256;     // 391
    const int NB_E = (NEDGES + 255) / 256;     // 6250
    const int NB_G = (NNODES + 63) / 64;       // 1563 (gemm)
    const int NB_A = (NNODES + 3) / 4;         // 25000 (agg)

    // CSR build
    hipLaunchKernelGGL(k_zero_counts, dim3(NB_N), dim3(256), 0, stream, counts);
    hipLaunchKernelGGL(k_count, dim3(NB_E), dim3(256), 0, stream, ei, counts);
    hipLaunchKernelGGL(k_dinv, dim3(NB_N), dim3(256), 0, stream, counts, dinv);
    hipLaunchKernelGGL(k_scan1, dim3(NB_N), dim3(256), 0, stream, counts, row_start, blockSums);
    hipLaunchKernelGGL(k_scan2, dim3(1), dim3(512), 0, stream, blockSums, NB_N);
    hipLaunchKernelGGL(k_scan3, dim3(NB_N), dim3(256), 0, stream, row_start, blockSums, cursor);
    hipLaunchKernelGGL(k_fill, dim3(NB_E), dim3(256), 0, stream, ei, dinv, cursor, csr);

    // conv1: gemm (fp16 out) + aggregate(+b1) -> z1 (fp32)
    hipLaunchKernelGGL((k_gemm128<false>), dim3(NB_G), dim3(256), 0, stream,
                       x, W1, h16, (const float*)nullptr, (const float*)nullptr);
    hipLaunchKernelGGL((k_aggh<false, true, false>), dim3(NB_A), dim3(256), 0, stream,
                       h16, dinv, row_start, counts, csr, b1,
                       (const float*)nullptr, (const float*)nullptr, zbuf, (__half*)nullptr);
    // BN1 stats over z1
    hipLaunchKernelGGL(k_zero_stats, dim3(1), dim3(256), 0, stream, colsum);
    hipLaunchKernelGGL(k_stats, dim3(1024), dim3(256), 0, stream, zbuf, colsum);
    hipLaunchKernelGGL(k_bn_finalize, dim3(1), dim3(128), 0, stream, colsum, g1, be1, scale, shift);

    // conv2: gemm (BN1+ReLU fused on A-load, fp16 out) + aggregate(+b2) -> z2 (fp32 + fp16 raw)
    hipLaunchKernelGGL((k_gemm128<true>), dim3(NB_G), dim3(256), 0, stream,
                       zbuf, W2, h16, scale, shift);
    hipLaunchKernelGGL((k_aggh<false, true, true>), dim3(NB_A), dim3(256), 0, stream,
                       h16, dinv, row_start, counts, csr, b2,
                       (const float*)nullptr, (const float*)nullptr, zbuf, z16);
    // BN2 stats over z2
    hipLaunchKernelGGL(k_zero_stats, dim3(1), dim3(256), 0, stream, colsum);
    hipLaunchKernelGGL(k_stats, dim3(1024), dim3(256), 0, stream, zbuf, colsum);
    hipLaunchKernelGGL(k_bn_finalize, dim3(1), dim3(128), 0, stream, colsum, g2, be2, scale, shift);

    // conv3 restructured: agg(act2) first (BN2+ReLU fused on fp16 gather), then GEMM->40+lsm.
    // agg(act @ Wf) == agg(act) @ Wf since aggregation is linear.
    hipLaunchKernelGGL((k_aggh<true, false, false>), dim3(NB_A), dim3(256), 0, stream,
                       z16, dinv, row_start, counts, csr, (const float*)nullptr,
                       scale, shift, zbuf, (__half*)nullptr);
    hipLaunchKernelGGL(k_gemm40_lsm, dim3(NB_G), dim3(256), 0, stream, zbuf, Wf, bf, out);
}